// Round 1
// baseline (468.891 us; speedup 1.0000x reference)
//
#include <hip/hip_runtime.h>
#include <cstdint>
#include <cstddef>

typedef unsigned short u16;
// Per guide §3: frag type for gfx950 mfma_f32_16x16x32_bf16 is 8 x short (4 VGPRs)
typedef short bf16x8 __attribute__((ext_vector_type(8)));
typedef float f32x4 __attribute__((ext_vector_type(4)));
typedef unsigned short u16x8 __attribute__((ext_vector_type(8)));

#define DEVINL __device__ __forceinline__

DEVINL u16 f2bf(float f) {
  union { float f; unsigned u; } v; v.f = f;
  unsigned r = v.u + 0x7FFFu + ((v.u >> 16) & 1u);
  return (u16)(r >> 16);
}
DEVINL float bf2f(u16 h) {
  union { unsigned u; float f; } v; v.u = ((unsigned)h) << 16;
  return v.f;
}
DEVINL float gelu_exact(float x) {
  return 0.5f * x * (1.0f + erff(x * 0.70710678118654752f));
}
DEVINL void gload_lds16(const void* g, void* l) {
  __builtin_amdgcn_global_load_lds(
      (const __attribute__((address_space(1))) void*)g,
      (__attribute__((address_space(3))) void*)l, 16, 0, 0);
}
DEVINL bf16x8 ld_frag(const u16* p) {
  return *reinterpret_cast<const bf16x8*>(p);
}

// ---------------------------------------------------------------- convert
__global__ __launch_bounds__(256) void conv_f32_bf16(
    const float* __restrict__ src, u16* __restrict__ dst, int n4) {
  int i = blockIdx.x * 256 + threadIdx.x;
  int stride = gridDim.x * 256;
  for (; i < n4; i += stride) {
    float4 v = reinterpret_cast<const float4*>(src)[i];
    ushort4 o;
    o.x = f2bf(v.x); o.y = f2bf(v.y); o.z = f2bf(v.z); o.w = f2bf(v.w);
    reinterpret_cast<ushort4*>(dst)[i] = o;
  }
}

// ---------------------------------------------------------------- GEMM (B^T)
// C[M][N] = A[M][K] * W[N][K]^T + bias, optional gelu, segment-routed outputs.
// BM=BN=128, BK=32, 256 threads = 4 waves (2x2), wave tile 64x64 = 4x4 frags.
struct EpiSeg {
  const float* bias;
  void* dst;
  int stride;
  int col_start;
  int do_gelu;
};
struct EpiTable { EpiSeg s[4]; int nseg; };

template <int F32OUT>
__global__ __launch_bounds__(256) void gemm_bt(
    const u16* __restrict__ A, const u16* __restrict__ W, int K, EpiTable et) {
  __shared__ u16 As[128 * 32];
  __shared__ u16 Bs[128 * 32];
  const int tid = threadIdx.x;
  const int lane = tid & 63;
  const int wv = tid >> 6;
  const int g = lane >> 4;
  const int c = lane & 15;
  const int wr = (wv >> 1) * 64;
  const int wc = (wv & 1) * 64;
  const long long rowBase = (long long)blockIdx.x * 128;
  const long long colBase = (long long)blockIdx.y * 128;

  f32x4 acc[4][4];
#pragma unroll
  for (int m = 0; m < 4; ++m)
#pragma unroll
    for (int n = 0; n < 4; ++n) acc[m][n] = {0.f, 0.f, 0.f, 0.f};

  // staging: idx = it*256+tid -> LDS 16B slot idx; row=idx>>2, sp=idx&3
  // source col-slot = sp ^ ((row>>1)&3)  (XOR swizzle -> 2-way-free frag reads)
  const int r0 = tid >> 2, sp0 = tid & 3;
  const int scol = (sp0 ^ ((r0 >> 1) & 3)) * 8;
  const u16* Ag = A + (rowBase + r0) * K + scol;
  const u16* Wg = W + (colBase + r0) * K + scol;
  u16* Al0 = As + tid * 8;
  u16* Al1 = As + (256 + tid) * 8;
  u16* Bl0 = Bs + tid * 8;
  u16* Bl1 = Bs + (256 + tid) * 8;
  const long long skip = 64LL * K;  // rows +64: swizzle unchanged

  // frag read offsets (elements)
  int aoff[4], boff[4];
#pragma unroll
  for (int m = 0; m < 4; ++m) {
    int row = wr + m * 16 + c;
    aoff[m] = row * 32 + ((g ^ ((row >> 1) & 3)) * 8);
    int rowb = wc + m * 16 + c;
    boff[m] = rowb * 32 + ((g ^ ((rowb >> 1) & 3)) * 8);
  }

  const int nk = K >> 5;
  for (int kt = 0; kt < nk; ++kt) {
    const int k0 = kt * 32;
    gload_lds16(Ag + k0, Al0);
    gload_lds16(Ag + skip + k0, Al1);
    gload_lds16(Wg + k0, Bl0);
    gload_lds16(Wg + skip + k0, Bl1);
    __syncthreads();  // staged (compiler drains vmcnt)
    bf16x8 a[4], b[4];
#pragma unroll
    for (int m = 0; m < 4; ++m) a[m] = ld_frag(&As[aoff[m]]);
#pragma unroll
    for (int n = 0; n < 4; ++n) b[n] = ld_frag(&Bs[boff[n]]);
#pragma unroll
    for (int m = 0; m < 4; ++m)
#pragma unroll
      for (int n = 0; n < 4; ++n)
        acc[m][n] = __builtin_amdgcn_mfma_f32_16x16x32_bf16(a[m], b[n], acc[m][n], 0, 0, 0);
    __syncthreads();  // compute done, safe to restage
  }

  // epilogue: pick segment by column tile
  EpiSeg e = et.s[0];
#pragma unroll
  for (int i = 1; i < 4; ++i)
    if (i < et.nseg && (int)colBase >= et.s[i].col_start) e = et.s[i];

#pragma unroll
  for (int m = 0; m < 4; ++m) {
#pragma unroll
    for (int n = 0; n < 4; ++n) {
      int col = (int)colBase + wc + n * 16 + c;
      int dcol = col - e.col_start;
      float bias = e.bias[dcol];
#pragma unroll
      for (int r = 0; r < 4; ++r) {
        long long row = rowBase + wr + m * 16 + g * 4 + r;
        float v = acc[m][n][r] + bias;
        if (e.do_gelu) v = gelu_exact(v);
        if (F32OUT)
          ((float*)e.dst)[row * e.stride + dcol] = v;
        else
          ((u16*)e.dst)[row * e.stride + dcol] = f2bf(v);
      }
    }
  }
}

// ---------------------------------------------------------------- RoPE + gelu
// reads cqr_t/ckr_t [8192][128] bf16, writes Q/K cols 384..511 (gelu applied)
__global__ __launch_bounds__(256) void rope_gelu_k(
    const u16* __restrict__ cqr, const u16* __restrict__ ckr,
    u16* __restrict__ Qb, u16* __restrict__ Kb) {
  int idx = blockIdx.x * 256 + threadIdx.x;  // 8192*64
  int row = idx >> 6, j = idx & 63;
  int s = row & 2047;
  float invf = exp2f(-(float)j * (13.287712379549449f / 64.f));  // 10000^{-j/64}
  float th = (float)s * invf;
  float sn, cs;
  sincosf(th, &sn, &cs);
  long long r128 = (long long)row * 128;
  float q1 = bf2f(cqr[r128 + j]), q2 = bf2f(cqr[r128 + 64 + j]);
  float k1 = bf2f(ckr[r128 + j]), k2 = bf2f(ckr[r128 + 64 + j]);
  float qo1 = q1 * cs - q2 * sn, qo2 = q2 * cs + q1 * sn;
  float ko1 = k1 * cs - k2 * sn, ko2 = k2 * cs + k1 * sn;
  long long rb = (long long)row * 512;
  Qb[rb + 384 + j] = f2bf(gelu_exact(qo1));
  Qb[rb + 448 + j] = f2bf(gelu_exact(qo2));
  Kb[rb + 384 + j] = f2bf(gelu_exact(ko1));
  Kb[rb + 448 + j] = f2bf(gelu_exact(ko2));
}

// ---------------------------------------------------------------- attention
// grid (16 q-tiles, 32 b*h), 256 thr = 4 waves; QB=128 (32 q-rows/wave), KVB=64.
__global__ __launch_bounds__(256) void attn_fwd(
    const u16* __restrict__ Q, const u16* __restrict__ Kin,
    const u16* __restrict__ V, u16* __restrict__ O) {
  const int qt = blockIdx.x;
  const int bh = blockIdx.y;
  const int b = bh >> 3, h = bh & 7;
  const int tid = threadIdx.x, lane = tid & 63, wv = tid >> 6;
  const int g = lane >> 4, c = lane & 15;

  __shared__ u16 Ks[64 * 64];   // swizzled d-slots
  __shared__ u16 Vt[64 * 72];   // transposed [d][kv], padded
  __shared__ u16 Ps[128 * 72];  // [q][kv], padded

  const long long rowB = (long long)b * 2048;
  const int qbase = qt * 128;
  const u16* Qp = Q + (rowB + qbase) * 512 + h * 64;
  const u16* Kp = Kin + rowB * 512 + h * 64;
  const u16* Vp = V + rowB * 512 + h * 64;

  // Q fragments (registers, hoisted)
  bf16x8 qa[2][2];
#pragma unroll
  for (int m = 0; m < 2; ++m)
#pragma unroll
    for (int kc = 0; kc < 2; ++kc)
      qa[m][kc] = ld_frag(Qp + (long long)(wv * 32 + m * 16 + c) * 512 + kc * 32 + g * 8);

  f32x4 o[2][4];
  float mrow[2][4], lrow[2][4];
#pragma unroll
  for (int m = 0; m < 2; ++m) {
#pragma unroll
    for (int nf = 0; nf < 4; ++nf) o[m][nf] = {0.f, 0.f, 0.f, 0.f};
#pragma unroll
    for (int r = 0; r < 4; ++r) { mrow[m][r] = -1e30f; lrow[m][r] = 0.f; }
  }

  const int kr0 = tid >> 3, ksp = tid & 7;
  const int ksrcd = (ksp ^ (kr0 & 7)) * 8;  // swizzled source col
  const int vkv0 = tid >> 3, vd0 = (tid & 7) * 8;

  const int ntiles = 2 * qt + 2;
  for (int t = 0; t < ntiles; ++t) {
    const int kvb = t * 64;
    // K tile -> LDS (swizzled source, linear dest)
    gload_lds16(Kp + (long long)(kvb + kr0) * 512 + ksrcd, Ks + tid * 8);
    gload_lds16(Kp + (long long)(kvb + kr0 + 32) * 512 + ksrcd, Ks + (256 + tid) * 8);
    // V tile -> regs
    u16x8 v0 = *reinterpret_cast<const u16x8*>(Vp + (long long)(kvb + vkv0) * 512 + vd0);
    u16x8 v1 = *reinterpret_cast<const u16x8*>(Vp + (long long)(kvb + vkv0 + 32) * 512 + vd0);
    __syncthreads();  // prev PV done -> Vt writable
#pragma unroll
    for (int i = 0; i < 8; ++i) {
      Vt[(vd0 + i) * 72 + vkv0] = v0[i];
      Vt[(vd0 + i) * 72 + vkv0 + 32] = v1[i];
    }
    __syncthreads();  // K staged + Vt written

    // S = Q K^T
    f32x4 s[2][4];
#pragma unroll
    for (int m = 0; m < 2; ++m)
#pragma unroll
      for (int nf = 0; nf < 4; ++nf) s[m][nf] = {0.f, 0.f, 0.f, 0.f};
#pragma unroll
    for (int kc = 0; kc < 2; ++kc) {
      bf16x8 kb[4];
#pragma unroll
      for (int nf = 0; nf < 4; ++nf) {
        int kvr = nf * 16 + c;
        int slot = (kc * 4 + g) ^ (kvr & 7);
        kb[nf] = ld_frag(&Ks[kvr * 64 + slot * 8]);
      }
#pragma unroll
      for (int m = 0; m < 2; ++m)
#pragma unroll
        for (int nf = 0; nf < 4; ++nf)
          s[m][nf] = __builtin_amdgcn_mfma_f32_16x16x32_bf16(qa[m][kc], kb[nf], s[m][nf], 0, 0, 0);
    }

    // scale + causal mask + online softmax
#pragma unroll
    for (int m = 0; m < 2; ++m) {
#pragma unroll
      for (int r = 0; r < 4; ++r) {
        int qrow = qbase + wv * 32 + m * 16 + g * 4 + r;
        float vmax = -1e30f;
#pragma unroll
        for (int nf = 0; nf < 4; ++nf) {
          int kvcol = kvb + nf * 16 + c;
          float sv = s[m][nf][r] * 0.125f;
          if (kvcol > qrow) sv = -1e30f;
          s[m][nf][r] = sv;
          vmax = fmaxf(vmax, sv);
        }
#pragma unroll
        for (int sh = 1; sh < 16; sh <<= 1)
          vmax = fmaxf(vmax, __shfl_xor(vmax, sh, 64));
        float mo = mrow[m][r];
        float mn = fmaxf(mo, vmax);
        float corr = __expf(mo - mn);
        float psum = 0.f;
#pragma unroll
        for (int nf = 0; nf < 4; ++nf) {
          float p = __expf(s[m][nf][r] - mn);
          s[m][nf][r] = p;
          psum += p;
        }
#pragma unroll
        for (int sh = 1; sh < 16; sh <<= 1)
          psum += __shfl_xor(psum, sh, 64);
        mrow[m][r] = mn;
        lrow[m][r] = lrow[m][r] * corr + psum;
#pragma unroll
        for (int nf = 0; nf < 4; ++nf) o[m][nf][r] *= corr;
      }
    }

    // P -> LDS (bf16)
#pragma unroll
    for (int m = 0; m < 2; ++m)
#pragma unroll
      for (int nf = 0; nf < 4; ++nf)
#pragma unroll
        for (int r = 0; r < 4; ++r)
          Ps[(wv * 32 + m * 16 + g * 4 + r) * 72 + nf * 16 + c] = f2bf(s[m][nf][r]);
    __syncthreads();  // P visible (K reads done -> next stage safe)

    // O += P V
#pragma unroll
    for (int kc2 = 0; kc2 < 2; ++kc2) {
      bf16x8 pa[2], vb[4];
#pragma unroll
      for (int m = 0; m < 2; ++m)
        pa[m] = ld_frag(&Ps[(wv * 32 + m * 16 + c) * 72 + kc2 * 32 + g * 8]);
#pragma unroll
      for (int nf = 0; nf < 4; ++nf)
        vb[nf] = ld_frag(&Vt[(nf * 16 + c) * 72 + kc2 * 32 + g * 8]);
#pragma unroll
      for (int m = 0; m < 2; ++m)
#pragma unroll
        for (int nf = 0; nf < 4; ++nf)
          o[m][nf] = __builtin_amdgcn_mfma_f32_16x16x32_bf16(pa[m], vb[nf], o[m][nf], 0, 0, 0);
    }
  }

  // normalize + store
#pragma unroll
  for (int m = 0; m < 2; ++m)
#pragma unroll
    for (int r = 0; r < 4; ++r) {
      float inv = 1.0f / lrow[m][r];
      long long row = rowB + qbase + wv * 32 + m * 16 + g * 4 + r;
#pragma unroll
      for (int nf = 0; nf < 4; ++nf) {
        int col = h * 64 + nf * 16 + c;
        O[row * 512 + col] = f2bf(o[m][nf][r] * inv);
      }
    }
}

// ---------------------------------------------------------------- launcher
extern "C" void kernel_launch(void* const* d_in, const int* in_sizes, int n_in,
                              void* d_out, int out_size, void* d_ws, size_t ws_size,
                              hipStream_t stream) {
  const float* x = (const float*)d_in[0];
  const float* CQ_w = (const float*)d_in[1];   const float* CQ_b = (const float*)d_in[2];
  const float* CQC_w = (const float*)d_in[3];  const float* CQC_b = (const float*)d_in[4];
  const float* CQR_w = (const float*)d_in[5];  const float* CQR_b = (const float*)d_in[6];
  const float* CKV_w = (const float*)d_in[7];  const float* CKV_b = (const float*)d_in[8];
  const float* CKR_w = (const float*)d_in[9];  const float* CKR_b = (const float*)d_in[10];
  const float* CKC_w = (const float*)d_in[11]; const float* CKC_b = (const float*)d_in[12];
  const float* CV_w = (const float*)d_in[13];  const float* CV_b = (const float*)d_in[14];
  const float* OUT_w = (const float*)d_in[15]; const float* OUT_b = (const float*)d_in[16];
  float* out = (float*)d_out;

  char* ws = (char*)d_ws;
  size_t off = 0;
  auto alloc = [&](size_t bytes) -> void* {
    void* p = ws + off;
    off += (bytes + 255) & ~(size_t)255;
    return p;
  };
  u16* xb   = (u16*)alloc(8192ULL * 2048 * 2);
  u16* Wc1  = (u16*)alloc(1280ULL * 2048 * 2);
  u16* Wcqc = (u16*)alloc(384ULL * 512 * 2);
  u16* Wc2  = (u16*)alloc(896ULL * 512 * 2);
  u16* Wout = (u16*)alloc(2048ULL * 512 * 2);
  u16* cq   = (u16*)alloc(8192ULL * 512 * 2);
  u16* ckv  = (u16*)alloc(8192ULL * 512 * 2);
  u16* cqrt = (u16*)alloc(8192ULL * 128 * 2);
  u16* ckrt = (u16*)alloc(8192ULL * 128 * 2);
  u16* Qb   = (u16*)alloc(8192ULL * 512 * 2);
  u16* Kbf  = (u16*)alloc(8192ULL * 512 * 2);
  u16* Vb   = (u16*)alloc(8192ULL * 512 * 2);
  u16* AO   = (u16*)alloc(8192ULL * 512 * 2);
  (void)ws_size; (void)in_sizes; (void)n_in; (void)out_size;

  auto conv = [&](const float* s, u16* d, long long n) {
    long long n4 = n / 4;
    int blocks = (int)((n4 + 255) / 256);
    if (blocks > 2048) blocks = 2048;
    conv_f32_bf16<<<blocks, 256, 0, stream>>>(s, d, (int)n4);
  };
  conv(x, xb, 8192LL * 2048);
  conv(CQ_w,  Wc1,                 512LL * 2048);
  conv(CKV_w, Wc1 + 512 * 2048,    512LL * 2048);
  conv(CQR_w, Wc1 + 1024 * 2048,   128LL * 2048);
  conv(CKR_w, Wc1 + 1152 * 2048,   128LL * 2048);
  conv(CQC_w, Wcqc, 384LL * 512);
  conv(CKC_w, Wc2, 384LL * 512);
  conv(CV_w,  Wc2 + 384 * 512, 512LL * 512);
  conv(OUT_w, Wout, 2048LL * 512);

  // GEMM1: x @ [CQ;CKV;CQR;CKR]^T  (N=1280, K=2048)
  EpiTable t1 = {};
  t1.nseg = 4;
  t1.s[0] = { CQ_b,  cq,   512, 0,    1 };
  t1.s[1] = { CKV_b, ckv,  512, 512,  1 };
  t1.s[2] = { CQR_b, cqrt, 128, 1024, 0 };
  t1.s[3] = { CKR_b, ckrt, 128, 1152, 0 };
  gemm_bt<0><<<dim3(64, 10), 256, 0, stream>>>(xb, Wc1, 2048, t1);

  // RoPE + gelu -> Q/K cols 384..511
  rope_gelu_k<<<dim3(8192 * 64 / 256), 256, 0, stream>>>(cqrt, ckrt, Qb, Kbf);

  // cqc: cq @ CQC^T -> Q[:,0:384] (gelu)
  EpiTable t2 = {};
  t2.nseg = 1;
  t2.s[0] = { CQC_b, Qb, 512, 0, 1 };
  gemm_bt<0><<<dim3(64, 3), 256, 0, stream>>>(cq, Wcqc, 512, t2);

  // ckv @ [CKC;CV]^T -> K[:,0:384] (gelu), V (bias only)
  EpiTable t3 = {};
  t3.nseg = 2;
  t3.s[0] = { CKC_b, Kbf, 512, 0, 1 };
  t3.s[1] = { CV_b,  Vb,  512, 384, 0 };
  gemm_bt<0><<<dim3(64, 7), 256, 0, stream>>>(ckv, Wc2, 512, t3);

  // attention
  attn_fwd<<<dim3(16, 32), 256, 0, stream>>>(Qb, Kbf, Vb, AO);

  // out: AO @ OUT^T -> d_out (fp32 + bias)
  EpiTable t4 = {};
  t4.nseg = 1;
  t4.s[0] = { OUT_b, out, 2048, 0, 0 };
  gemm_bt<1><<<dim3(64, 16), 256, 0, stream>>>(AO, Wout, 512, t4);
}

// Round 7
// 447.696 us; speedup vs baseline: 1.0473x; 1.0473x over previous
//
#include <hip/hip_runtime.h>
#include <cstdint>
#include <cstddef>

typedef unsigned short u16;
typedef short bf16x8 __attribute__((ext_vector_type(8)));
typedef float f32x4 __attribute__((ext_vector_type(4)));
typedef unsigned short u16x8 __attribute__((ext_vector_type(8)));

#define DEVINL __device__ __forceinline__

DEVINL u16 f2bf(float f) {
  union { float f; unsigned u; } v; v.f = f;
  unsigned r = v.u + 0x7FFFu + ((v.u >> 16) & 1u);
  return (u16)(r >> 16);
}
DEVINL float bf2f(u16 h) {
  union { unsigned u; float f; } v; v.u = ((unsigned)h) << 16;
  return v.f;
}
DEVINL float gelu_exact(float x) {
  return 0.5f * x * (1.0f + erff(x * 0.70710678118654752f));
}
DEVINL void gload_lds16(const void* g, void* l) {
  __builtin_amdgcn_global_load_lds(
      (const __attribute__((address_space(1))) void*)g,
      (__attribute__((address_space(3))) void*)l, 16, 0, 0);
}
DEVINL bf16x8 ld_frag(const u16* p) {
  return *reinterpret_cast<const bf16x8*>(p);
}

// ---------------------------------------------------------------- convert x
__global__ __launch_bounds__(256) void conv_f32_bf16(
    const float* __restrict__ src, u16* __restrict__ dst, int n4) {
  int i = blockIdx.x * 256 + threadIdx.x;
  int stride = gridDim.x * 256;
  for (; i < n4; i += stride) {
    float4 v = reinterpret_cast<const float4*>(src)[i];
    ushort4 o;
    o.x = f2bf(v.x); o.y = f2bf(v.y); o.z = f2bf(v.z); o.w = f2bf(v.w);
    reinterpret_cast<ushort4*>(dst)[i] = o;
  }
}

// ------------------------------------------------- fused weight converts
// 8 segments, each block converts 1024 float4s (4 per thread).
struct ConvTab {
  const float* src[8];
  u16* dst[8];
  int bstart[8];  // first block id of each segment
};
__global__ __launch_bounds__(256) void conv_w_fused(ConvTab t) {
  int blk = blockIdx.x;
  int seg = 0;
#pragma unroll
  for (int i = 1; i < 8; ++i)
    if (blk >= t.bstart[i]) seg = i;
  const float* src = t.src[seg];
  u16* dst = t.dst[seg];
  int base = (blk - t.bstart[seg]) * 1024 + threadIdx.x;
#pragma unroll
  for (int k = 0; k < 4; ++k) {
    int i = base + k * 256;
    float4 v = reinterpret_cast<const float4*>(src)[i];
    ushort4 o;
    o.x = f2bf(v.x); o.y = f2bf(v.y); o.z = f2bf(v.z); o.w = f2bf(v.w);
    reinterpret_cast<ushort4*>(dst)[i] = o;
  }
}

// ---------------------------------------------------------------- GEMM (B^T)
struct EpiSeg {
  const float* bias;
  void* dst;
  int stride;
  int col_start;
  int do_gelu;
};
struct EpiTable { EpiSeg s[4]; int nseg; };

template <int F32OUT>
__global__ __launch_bounds__(256) void gemm_bt(
    const u16* __restrict__ A, const u16* __restrict__ W, int K, EpiTable et) {
  __shared__ u16 As[128 * 32];
  __shared__ u16 Bs[128 * 32];
  const int tid = threadIdx.x;
  const int lane = tid & 63;
  const int wv = tid >> 6;
  const int g = lane >> 4;
  const int c = lane & 15;
  const int wr = (wv >> 1) * 64;
  const int wc = (wv & 1) * 64;

  // XCD-aware swizzle (all launch grids are %8==0)
  int bx = blockIdx.x, by = blockIdx.y;
  {
    int nwg = gridDim.x * gridDim.y;
    if ((nwg & 7) == 0) {
      int lid = by * gridDim.x + bx;
      int qq = nwg >> 3;
      int swz = (lid & 7) * qq + (lid >> 3);
      bx = swz % gridDim.x;
      by = swz / gridDim.x;
    }
  }
  const long long rowBase = (long long)bx * 128;
  const long long colBase = (long long)by * 128;

  f32x4 acc[4][4];
#pragma unroll
  for (int m = 0; m < 4; ++m)
#pragma unroll
    for (int n = 0; n < 4; ++n) acc[m][n] = {0.f, 0.f, 0.f, 0.f};

  const int r0 = tid >> 2, sp0 = tid & 3;
  const int scol = (sp0 ^ ((r0 >> 1) & 3)) * 8;
  const u16* Ag = A + (rowBase + r0) * K + scol;
  const u16* Wg = W + (colBase + r0) * K + scol;
  u16* Al0 = As + tid * 8;
  u16* Al1 = As + (256 + tid) * 8;
  u16* Bl0 = Bs + tid * 8;
  u16* Bl1 = Bs + (256 + tid) * 8;
  const long long skip = 64LL * K;

  int aoff[4], boff[4];
#pragma unroll
  for (int m = 0; m < 4; ++m) {
    int row = wr + m * 16 + c;
    aoff[m] = row * 32 + ((g ^ ((row >> 1) & 3)) * 8);
    int rowb = wc + m * 16 + c;
    boff[m] = rowb * 32 + ((g ^ ((rowb >> 1) & 3)) * 8);
  }

  const int nk = K >> 5;
  for (int kt = 0; kt < nk; ++kt) {
    const int k0 = kt * 32;
    gload_lds16(Ag + k0, Al0);
    gload_lds16(Ag + skip + k0, Al1);
    gload_lds16(Wg + k0, Bl0);
    gload_lds16(Wg + skip + k0, Bl1);
    __syncthreads();
    bf16x8 a[4], b[4];
#pragma unroll
    for (int m = 0; m < 4; ++m) a[m] = ld_frag(&As[aoff[m]]);
#pragma unroll
    for (int n = 0; n < 4; ++n) b[n] = ld_frag(&Bs[boff[n]]);
#pragma unroll
    for (int m = 0; m < 4; ++m)
#pragma unroll
      for (int n = 0; n < 4; ++n)
        acc[m][n] = __builtin_amdgcn_mfma_f32_16x16x32_bf16(a[m], b[n], acc[m][n], 0, 0, 0);
    __syncthreads();
  }

  EpiSeg e = et.s[0];
#pragma unroll
  for (int i = 1; i < 4; ++i)
    if (i < et.nseg && (int)colBase >= et.s[i].col_start) e = et.s[i];

#pragma unroll
  for (int m = 0; m < 4; ++m) {
#pragma unroll
    for (int n = 0; n < 4; ++n) {
      int col = (int)colBase + wc + n * 16 + c;
      int dcol = col - e.col_start;
      float bias = e.bias[dcol];
#pragma unroll
      for (int r = 0; r < 4; ++r) {
        long long row = rowBase + wr + m * 16 + g * 4 + r;
        float v = acc[m][n][r] + bias;
        if (e.do_gelu) v = gelu_exact(v);
        if (F32OUT)
          ((float*)e.dst)[row * e.stride + dcol] = v;
        else
          ((u16*)e.dst)[row * e.stride + dcol] = f2bf(v);
      }
    }
  }
}

// ---------------------------------------------------------------- RoPE + gelu
__global__ __launch_bounds__(256) void rope_gelu_k(
    const u16* __restrict__ cqr, const u16* __restrict__ ckr,
    u16* __restrict__ Qb, u16* __restrict__ Kb) {
  int idx = blockIdx.x * 256 + threadIdx.x;  // 8192*64
  int row = idx >> 6, j = idx & 63;
  int s = row & 2047;
  float invf = exp2f(-(float)j * (13.287712379549449f / 64.f));
  float th = (float)s * invf;
  float sn, cs;
  sincosf(th, &sn, &cs);
  long long r128 = (long long)row * 128;
  float q1 = bf2f(cqr[r128 + j]), q2 = bf2f(cqr[r128 + 64 + j]);
  float k1 = bf2f(ckr[r128 + j]), k2 = bf2f(ckr[r128 + 64 + j]);
  float qo1 = q1 * cs - q2 * sn, qo2 = q2 * cs + q1 * sn;
  float ko1 = k1 * cs - k2 * sn, ko2 = k2 * cs + k1 * sn;
  long long rb = (long long)row * 512;
  Qb[rb + 384 + j] = f2bf(gelu_exact(qo1));
  Qb[rb + 448 + j] = f2bf(gelu_exact(qo2));
  Kb[rb + 384 + j] = f2bf(gelu_exact(ko1));
  Kb[rb + 448 + j] = f2bf(gelu_exact(ko2));
}

// ---------------------------------------------------------------- attention
// Diagonal-paired causal flash attention.
// Block = 4 waves (256 thr), handles q-tiles p (rows p*64..) AND 31-p.
// Each wave: 16 q-rows per tile. KV tile = 64. Work per block = 33 or 34
// KV-tile units regardless of p -> balanced grid of 512 blocks.
__global__ __launch_bounds__(256) void attn_fwd(
    const u16* __restrict__ Q, const u16* __restrict__ Kin,
    const u16* __restrict__ V, u16* __restrict__ O) {
  const int p = blockIdx.x;        // pair id 0..15
  const int bh = blockIdx.y;
  const int b = bh >> 3, h = bh & 7;
  const int tid = threadIdx.x, lane = tid & 63, wv = tid >> 6;
  const int g = lane >> 4, c = lane & 15;

  __shared__ u16 Ks[64 * 64];      // [kv][d-slot swizzled]
  __shared__ u16 Vt[64 * 72];      // [d][kv] transposed, padded
  __shared__ u16 Ps[2][64 * 72];   // [tile][q][kv], padded

  const long long rowB = (long long)b * 2048;
  const int qb[2] = { p * 64, (31 - p) * 64 };
  const u16* Kp = Kin + rowB * 512 + h * 64;
  const u16* Vp = V + rowB * 512 + h * 64;

  // Q fragments (A-operand: lane holds Q[row=c][k=g*8..+7])
  bf16x8 qa[2][2];
#pragma unroll
  for (int tl = 0; tl < 2; ++tl) {
    const u16* Qp = Q + (rowB + qb[tl] + wv * 16 + c) * 512 + h * 64;
#pragma unroll
    for (int kc = 0; kc < 2; ++kc)
      qa[tl][kc] = ld_frag(Qp + kc * 32 + g * 8);
  }

  f32x4 o[2][4];
  float m_[2][4], l_[2][4];
#pragma unroll
  for (int tl = 0; tl < 2; ++tl) {
#pragma unroll
    for (int nf = 0; nf < 4; ++nf) o[tl][nf] = {0.f, 0.f, 0.f, 0.f};
#pragma unroll
    for (int r = 0; r < 4; ++r) { m_[tl][r] = -1e30f; l_[tl][r] = 0.f; }
  }

  const int kr0 = tid >> 3, ksp = tid & 7;
  const int ksrc = (ksp ^ (kr0 & 7)) * 8;
  const int vkv0 = tid >> 3, vd0 = (tid & 7) * 8;
  const float SCL2 = 0.18033688011112042f;  // 0.125 * log2(e)

  const int nt = 32 - p;  // tile B = 31-p needs kv-tiles 0..31-p
  for (int t = 0; t < nt; ++t) {
    const int kvb = t * 64;
    const bool doA = (t <= p);
    // K tile -> LDS (swizzled source, linear dest)
    gload_lds16(Kp + (long long)(kvb + kr0) * 512 + ksrc, Ks + tid * 8);
    gload_lds16(Kp + (long long)(kvb + kr0 + 32) * 512 + ksrc, Ks + (256 + tid) * 8);
    // V tile -> regs
    u16x8 v0 = *reinterpret_cast<const u16x8*>(Vp + (long long)(kvb + vkv0) * 512 + vd0);
    u16x8 v1 = *reinterpret_cast<const u16x8*>(Vp + (long long)(kvb + vkv0 + 32) * 512 + vd0);
    __syncthreads();  // prev PV done -> Vt writable
#pragma unroll
    for (int i = 0; i < 8; ++i) {
      Vt[(vd0 + i) * 72 + vkv0] = v0[i];
      Vt[(vd0 + i) * 72 + vkv0 + 32] = v1[i];
    }
    __syncthreads();  // K staged + Vt written

    // S = Q K^T for both tiles (K frags loaded once, shared)
    f32x4 s[2][4];
#pragma unroll
    for (int tl = 0; tl < 2; ++tl)
#pragma unroll
      for (int nf = 0; nf < 4; ++nf) s[tl][nf] = {0.f, 0.f, 0.f, 0.f};
#pragma unroll
    for (int kc = 0; kc < 2; ++kc) {
      bf16x8 kb[4];
#pragma unroll
      for (int nf = 0; nf < 4; ++nf) {
        int kvr = nf * 16 + c;
        int slot = (kc * 4 + g) ^ (kvr & 7);
        kb[nf] = ld_frag(&Ks[kvr * 64 + slot * 8]);
      }
#pragma unroll
      for (int nf = 0; nf < 4; ++nf)
        s[1][nf] = __builtin_amdgcn_mfma_f32_16x16x32_bf16(qa[1][kc], kb[nf], s[1][nf], 0, 0, 0);
      if (doA) {
#pragma unroll
        for (int nf = 0; nf < 4; ++nf)
          s[0][nf] = __builtin_amdgcn_mfma_f32_16x16x32_bf16(qa[0][kc], kb[nf], s[0][nf], 0, 0, 0);
      }
    }

    // online softmax per tile (exp2 domain), then P -> LDS
#pragma unroll
    for (int tl = 0; tl < 2; ++tl) {
      if (tl == 0 && !doA) continue;
      const bool diag = (tl == 0) ? (t == p) : (t == nt - 1);
      const int qr0 = qb[tl] + wv * 16 + g * 4;
#pragma unroll
      for (int r = 0; r < 4; ++r) {
        float vmax = -1e30f;
#pragma unroll
        for (int nf = 0; nf < 4; ++nf) {
          float sv = s[tl][nf][r] * SCL2;
          if (diag && (kvb + nf * 16 + c > qr0 + r)) sv = -1e30f;
          s[tl][nf][r] = sv;
          vmax = fmaxf(vmax, sv);
        }
#pragma unroll
        for (int sh = 1; sh < 16; sh <<= 1)
          vmax = fmaxf(vmax, __shfl_xor(vmax, sh, 64));
        float mo = m_[tl][r];
        float mn = fmaxf(mo, vmax);
        float corr = exp2f(mo - mn);
        float ps = 0.f;
#pragma unroll
        for (int nf = 0; nf < 4; ++nf) {
          float pv = exp2f(s[tl][nf][r] - mn);
          s[tl][nf][r] = pv;
          ps += pv;
        }
#pragma unroll
        for (int sh = 1; sh < 16; sh <<= 1)
          ps += __shfl_xor(ps, sh, 64);
        m_[tl][r] = mn;
        l_[tl][r] = l_[tl][r] * corr + ps;
#pragma unroll
        for (int nf = 0; nf < 4; ++nf) o[tl][nf][r] *= corr;
      }
#pragma unroll
      for (int nf = 0; nf < 4; ++nf)
#pragma unroll
        for (int r = 0; r < 4; ++r)
          Ps[tl][(wv * 16 + g * 4 + r) * 72 + nf * 16 + c] = f2bf(s[tl][nf][r]);
    }
    __syncthreads();  // P visible; K reads done

    // O += P V  (V frags loaded once, shared by both tiles)
#pragma unroll
    for (int kc2 = 0; kc2 < 2; ++kc2) {
      bf16x8 vb[4];
#pragma unroll
      for (int nf = 0; nf < 4; ++nf)
        vb[nf] = ld_frag(&Vt[(nf * 16 + c) * 72 + kc2 * 32 + g * 8]);
      bf16x8 pb = ld_frag(&Ps[1][(wv * 16 + c) * 72 + kc2 * 32 + g * 8]);
#pragma unroll
      for (int nf = 0; nf < 4; ++nf)
        o[1][nf] = __builtin_amdgcn_mfma_f32_16x16x32_bf16(pb, vb[nf], o[1][nf], 0, 0, 0);
      if (doA) {
        bf16x8 pa = ld_frag(&Ps[0][(wv * 16 + c) * 72 + kc2 * 32 + g * 8]);
#pragma unroll
        for (int nf = 0; nf < 4; ++nf)
          o[0][nf] = __builtin_amdgcn_mfma_f32_16x16x32_bf16(pa, vb[nf], o[0][nf], 0, 0, 0);
      }
    }
  }

  // normalize + store both tiles
#pragma unroll
  for (int tl = 0; tl < 2; ++tl) {
#pragma unroll
    for (int r = 0; r < 4; ++r) {
      float inv = 1.0f / l_[tl][r];
      long long row = rowB + qb[tl] + wv * 16 + g * 4 + r;
#pragma unroll
      for (int nf = 0; nf < 4; ++nf)
        O[row * 512 + h * 64 + nf * 16 + c] = f2bf(o[tl][nf][r] * inv);
    }
  }
}

// ---------------------------------------------------------------- launcher
extern "C" void kernel_launch(void* const* d_in, const int* in_sizes, int n_in,
                              void* d_out, int out_size, void* d_ws, size_t ws_size,
                              hipStream_t stream) {
  const float* x = (const float*)d_in[0];
  const float* CQ_w = (const float*)d_in[1];   const float* CQ_b = (const float*)d_in[2];
  const float* CQC_w = (const float*)d_in[3];  const float* CQC_b = (const float*)d_in[4];
  const float* CQR_w = (const float*)d_in[5];  const float* CQR_b = (const float*)d_in[6];
  const float* CKV_w = (const float*)d_in[7];  const float* CKV_b = (const float*)d_in[8];
  const float* CKR_w = (const float*)d_in[9];  const float* CKR_b = (const float*)d_in[10];
  const float* CKC_w = (const float*)d_in[11]; const float* CKC_b = (const float*)d_in[12];
  const float* CV_w = (const float*)d_in[13];  const float* CV_b = (const float*)d_in[14];
  const float* OUT_w = (const float*)d_in[15]; const float* OUT_b = (const float*)d_in[16];
  float* out = (float*)d_out;

  char* ws = (char*)d_ws;
  size_t off = 0;
  auto alloc = [&](size_t bytes) -> void* {
    void* pp = ws + off;
    off += (bytes + 255) & ~(size_t)255;
    return pp;
  };
  u16* xb   = (u16*)alloc(8192ULL * 2048 * 2);
  u16* Wc1  = (u16*)alloc(1280ULL * 2048 * 2);
  u16* Wcqc = (u16*)alloc(384ULL * 512 * 2);
  u16* Wc2  = (u16*)alloc(896ULL * 512 * 2);
  u16* Wout = (u16*)alloc(2048ULL * 512 * 2);
  u16* cq   = (u16*)alloc(8192ULL * 512 * 2);
  u16* ckv  = (u16*)alloc(8192ULL * 512 * 2);
  u16* cqrt = (u16*)alloc(8192ULL * 128 * 2);
  u16* ckrt = (u16*)alloc(8192ULL * 128 * 2);
  u16* Qb   = (u16*)alloc(8192ULL * 512 * 2);
  u16* Kbf  = (u16*)alloc(8192ULL * 512 * 2);
  u16* Vb   = (u16*)alloc(8192ULL * 512 * 2);
  u16* AO   = (u16*)alloc(8192ULL * 512 * 2);
  (void)ws_size; (void)in_sizes; (void)n_in; (void)out_size;

  // x convert (16.8M elems)
  conv_f32_bf16<<<2048, 256, 0, stream>>>(x, xb, 8192 * 2048 / 4);

  // all 8 weight converts in one launch (block = 1024 float4s)
  ConvTab ct;
  ct.src[0] = CQ_w;  ct.dst[0] = Wc1;               // 512x2048 -> 256 blk
  ct.src[1] = CKV_w; ct.dst[1] = Wc1 + 512 * 2048;  // 256 blk
  ct.src[2] = CQR_w; ct.dst[2] = Wc1 + 1024 * 2048; // 128x2048 -> 64 blk
  ct.src[3] = CKR_w; ct.dst[3] = Wc1 + 1152 * 2048; // 64 blk
  ct.src[4] = CQC_w; ct.dst[4] = Wcqc;              // 384x512 -> 48 blk
  ct.src[5] = CKC_w; ct.dst[5] = Wc2;               // 48 blk
  ct.src[6] = CV_w;  ct.dst[6] = Wc2 + 384 * 512;   // 512x512 -> 64 blk
  ct.src[7] = OUT_w; ct.dst[7] = Wout;              // 2048x512 -> 256 blk
  int bs = 0;
  int nblk[8] = {256, 256, 64, 64, 48, 48, 64, 256};
  for (int i = 0; i < 8; ++i) { ct.bstart[i] = bs; bs += nblk[i]; }
  conv_w_fused<<<bs, 256, 0, stream>>>(ct);

  // GEMM1: x @ [CQ;CKV;CQR;CKR]^T  (N=1280, K=2048)
  EpiTable t1 = {};
  t1.nseg = 4;
  t1.s[0] = { CQ_b,  cq,   512, 0,    1 };
  t1.s[1] = { CKV_b, ckv,  512, 512,  1 };
  t1.s[2] = { CQR_b, cqrt, 128, 1024, 0 };
  t1.s[3] = { CKR_b, ckrt, 128, 1152, 0 };
  gemm_bt<0><<<dim3(64, 10), 256, 0, stream>>>(xb, Wc1, 2048, t1);

  rope_gelu_k<<<dim3(8192 * 64 / 256), 256, 0, stream>>>(cqrt, ckrt, Qb, Kbf);

  EpiTable t2 = {};
  t2.nseg = 1;
  t2.s[0] = { CQC_b, Qb, 512, 0, 1 };
  gemm_bt<0><<<dim3(64, 3), 256, 0, stream>>>(cq, Wcqc, 512, t2);

  EpiTable t3 = {};
  t3.nseg = 2;
  t3.s[0] = { CKC_b, Kbf, 512, 0, 1 };
  t3.s[1] = { CV_b,  Vb,  512, 384, 0 };
  gemm_bt<0><<<dim3(64, 7), 256, 0, stream>>>(ckv, Wc2, 512, t3);

  attn_fwd<<<dim3(16, 32), 256, 0, stream>>>(Qb, Kbf, Vb, AO);

  EpiTable t4 = {};
  t4.nseg = 1;
  t4.s[0] = { OUT_b, out, 2048, 0, 0 };
  gemm_bt<1><<<dim3(64, 16), 256, 0, stream>>>(AO, Wout, 512, t4);
}